// Round 6
// baseline (347.940 us; speedup 1.0000x reference)
//
#include <hip/hip_runtime.h>
#include <math.h>

#define TT 512
#define GG 3
#define HH 32
#define DD 128

typedef _Float16 half8 __attribute__((ext_vector_type(8)));
typedef float f32x4 __attribute__((ext_vector_type(4)));

__device__ __forceinline__ float fast_tanh(float x) {
  float e = __expf(2.0f * x);
  return 1.0f - 2.0f * __builtin_amdgcn_rcpf(1.0f + e);
}

__device__ __forceinline__ uint32_t pack_half2(float a, float b) {
  auto p = __builtin_amdgcn_cvt_pkrtz(a, b);   // __fp16 ext_vector(2)
  return __builtin_bit_cast(uint32_t, p);
}

// 16 sequences (same g) per block of 2 waves; wave w owns j-tile [16w,16w+16).
// All of x for the block is preloaded to LDS, so the 512-step loop issues ZERO
// global loads -> the implicit s_waitcnt vmcnt(0) before each s_barrier drains
// nothing. Per step per wave: ds_read h + x, 3x mfma_f32_16x16x32_f16,
// 24 transcendentals, ds_write its 16-j half of h_new (fp16), 1 barrier.
__global__ __launch_bounds__(128) void gru_scan_mfma(
    const float* __restrict__ x, const float* __restrict__ W_ih,
    const float* __restrict__ W_hh, const float* __restrict__ b_ih,
    const float* __restrict__ b_hh, float* __restrict__ hout, int B) {
  const int tid = threadIdx.x;
  const int w = tid >> 6;      // j-tile of this wave
  const int lane = tid & 63;
  const int col = lane & 15;   // seq for B/C; m-row for A
  const int grp = lane >> 4;   // k-block for A/B; row-group for C
  const int nb = B / 16;
  const int g = blockIdx.x / nb;
  const int b0 = (blockIdx.x % nb) * 16;
  const float L2E = 1.44269504088896340736f;

  // ---- x staging: [seq][t], leading dim 513 so bank = (col+t)%32 (no conflict)
  __shared__ float xlds[16][TT + 1];
  // ---- double-buffered fp16 h in LDS: [buf][seq][16 words + 4 pad] ----
  __shared__ uint32_t hbuf[2][16][20];

#pragma unroll 4
  for (int i = tid; i < 16 * TT; i += 128) {
    int s = i >> 9, t = i & (TT - 1);
    xlds[s][t] = x[((size_t)(b0 + s) * TT + t) * GG + g];
  }

  // ---- A fragments for this wave's j-tile (pre-scaled for exp2) ----
  half8 Af[3];
  const float* Wg = W_hh + (size_t)g * 3 * HH * HH;
#pragma unroll
  for (int gam = 0; gam < 3; ++gam) {
    const float sc = (gam == 2) ? 2.0f * L2E : -L2E;
    const float* src = Wg + (size_t)(gam * 32 + w * 16 + col) * HH + grp * 8;
    half8 a;
#pragma unroll
    for (int i = 0; i < 8; ++i) a[i] = (_Float16)(src[i] * sc);
    Af[gam] = a;
  }

  // ---- per-lane gate constants for j = w*16 + grp*4 + r ----
  float wiR[4], wiZ[4], wiN[4], bR[4], bZ[4], bN[4], bHN[4];
#pragma unroll
  for (int r = 0; r < 4; ++r) {
    int j = w * 16 + grp * 4 + r;
    wiR[r] = W_ih[g * 96 + j] * (-L2E);
    wiZ[r] = W_ih[g * 96 + 32 + j] * (-L2E);
    wiN[r] = W_ih[g * 96 + 64 + j] * (2.0f * L2E);
    bR[r] = (b_ih[g * 96 + j] + b_hh[g * 96 + j]) * (-L2E);
    bZ[r] = (b_ih[g * 96 + 32 + j] + b_hh[g * 96 + 32 + j]) * (-L2E);
    bN[r] = b_ih[g * 96 + 64 + j] * (2.0f * L2E);
    bHN[r] = b_hh[g * 96 + 64 + j] * (2.0f * L2E);
  }

  float ho[4];
#pragma unroll
  for (int r = 0; r < 4; ++r) ho[r] = 0.0f;
  for (int i = tid; i < 320; i += 128) ((uint32_t*)hbuf)[i] = 0u;  // zero buf 0
  __syncthreads();

  const f32x4 zero = {0.f, 0.f, 0.f, 0.f};

#define GRU_STEP(SRC, DST, TCUR)                                               \
  {                                                                            \
    float xcur = xlds[col][TCUR];                                              \
    half8 Bf = *(const half8*)&hbuf[SRC][col][grp * 4];                        \
    f32x4 Cr = __builtin_amdgcn_mfma_f32_16x16x32_f16(Af[0], Bf, zero, 0, 0, 0); \
    f32x4 Cz = __builtin_amdgcn_mfma_f32_16x16x32_f16(Af[1], Bf, zero, 0, 0, 0); \
    f32x4 Cn = __builtin_amdgcn_mfma_f32_16x16x32_f16(Af[2], Bf, zero, 0, 0, 0); \
    _Pragma("unroll") for (int r = 0; r < 4; ++r) {                            \
      float pr = Cr[r] + fmaf(xcur, wiR[r], bR[r]);                            \
      float rr = __builtin_amdgcn_rcpf(1.0f + __builtin_amdgcn_exp2f(pr));     \
      float pz = Cz[r] + fmaf(xcur, wiZ[r], bZ[r]);                            \
      float zz = __builtin_amdgcn_rcpf(1.0f + __builtin_amdgcn_exp2f(pz));     \
      float tnv = Cn[r] + bHN[r];                                              \
      float pn = fmaf(rr, tnv, fmaf(xcur, wiN[r], bN[r]));                     \
      float u = __builtin_amdgcn_rcpf(1.0f + __builtin_amdgcn_exp2f(pn));      \
      float nn = fmaf(-2.0f, u, 1.0f);                                        \
      ho[r] = fmaf(zz, ho[r] - nn, nn);                                        \
    }                                                                          \
    uint2 wpk;                                                                 \
    wpk.x = pack_half2(ho[0], ho[1]);                                          \
    wpk.y = pack_half2(ho[2], ho[3]);                                          \
    *(uint2*)&hbuf[DST][col][w * 8 + grp * 2] = wpk;                           \
    __syncthreads();                                                           \
  }

#pragma unroll 1
  for (int t = 0; t < TT; t += 2) {
    GRU_STEP(0, 1, t)
    GRU_STEP(1, 0, t + 1)
  }
#undef GRU_STEP

#pragma unroll
  for (int r = 0; r < 4; ++r) {
    int j = w * 16 + grp * 4 + r;
    hout[((size_t)(b0 + col) * GG + g) * HH + j] = ho[r];
  }
}

// One block per b: query -> scores -> softmax -> weighted rep -> out row,
// then broadcast-write the row across all T positions (coalesced float4).
__global__ __launch_bounds__(256) void epilogue(
    const float* __restrict__ ctx, const float* __restrict__ hf,
    const float* __restrict__ Wq, const float* __restrict__ bq,
    const float* __restrict__ Ws, const float* __restrict__ bs,
    const float* __restrict__ Wo, const float* __restrict__ bo,
    const float* __restrict__ logT, float* __restrict__ out, int B) {
  const int b = blockIdx.x;
  const int tid = threadIdx.x;
  __shared__ float sc[DD];
  __shared__ float sw[HH];
  __shared__ float srow[DD];
  if (tid < DD) sc[tid] = ctx[(size_t)b * DD + tid];
  __syncthreads();
  if (tid < HH) {
    float q = bq[tid];
#pragma unroll 4
    for (int d = 0; d < DD; ++d) q = fmaf(sc[d], Wq[d * HH + tid], q);
    float h0 = hf[((size_t)b * 3 + 0) * HH + tid];
    float h1 = hf[((size_t)b * 3 + 1) * HH + tid];
    float h2 = hf[((size_t)b * 3 + 2) * HH + tid];
    float wsv = Ws[tid];
    float s0 = fast_tanh(h0 + q) * wsv;
    float s1 = fast_tanh(h1 + q) * wsv;
    float s2 = fast_tanh(h2 + q) * wsv;
#pragma unroll
    for (int off = 16; off >= 1; off >>= 1) {
      s0 += __shfl_xor(s0, off, 32);
      s1 += __shfl_xor(s1, off, 32);
      s2 += __shfl_xor(s2, off, 32);
    }
    float bsv = bs[0];
    float tmp = fmaxf(__expf(logT[0]), 0.1f);
    float inv = 1.0f / tmp;
    s0 = (s0 + bsv) * inv; s1 = (s1 + bsv) * inv; s2 = (s2 + bsv) * inv;
    float m = fmaxf(s0, fmaxf(s1, s2));
    float e0 = __expf(s0 - m), e1 = __expf(s1 - m), e2 = __expf(s2 - m);
    float den = 1.0f / (e0 + e1 + e2);
    float a0 = e0 * den, a1 = e1 * den, a2 = e2 * den;
    sw[tid] = a0 * h0 + a1 * h1 + a2 * h2;
    if (tid == 0) {
      size_t aoff = (size_t)B * TT * DD + (size_t)b * 3;
      out[aoff] = a0; out[aoff + 1] = a1; out[aoff + 2] = a2;
    }
  }
  __syncthreads();
  if (tid < DD) {
    float o = bo[tid];
#pragma unroll
    for (int h = 0; h < HH; ++h) o = fmaf(sw[h], Wo[h * DD + tid], o);
    srow[tid] = o;
  }
  __syncthreads();
  const float4 v = *(const float4*)&srow[(tid & 31) * 4];
  float4* o4 = (float4*)out + (size_t)b * (TT * DD / 4);
#pragma unroll 4
  for (int i = tid; i < TT * DD / 4; i += 256) {
    o4[i] = v;
  }
}

extern "C" void kernel_launch(void* const* d_in, const int* in_sizes, int n_in,
                              void* d_out, int out_size, void* d_ws, size_t ws_size,
                              hipStream_t stream) {
  const float* x    = (const float*)d_in[0];
  const float* ctx  = (const float*)d_in[1];
  const float* W_ih = (const float*)d_in[2];
  const float* W_hh = (const float*)d_in[3];
  const float* b_ih = (const float*)d_in[4];
  const float* b_hh = (const float*)d_in[5];
  const float* Wq   = (const float*)d_in[6];
  const float* bq   = (const float*)d_in[7];
  const float* Ws   = (const float*)d_in[8];
  const float* bs   = (const float*)d_in[9];
  const float* Wo   = (const float*)d_in[10];
  const float* bo   = (const float*)d_in[11];
  const float* logT = (const float*)d_in[12];
  float* out = (float*)d_out;
  const int B = in_sizes[0] / (TT * GG);

  float* hf = (float*)d_ws;  // B*G*H floats

  dim3 g1((B / 16) * GG);
  gru_scan_mfma<<<g1, 128, 0, stream>>>(x, W_ih, W_hh, b_ih, b_hh, hf, B);
  epilogue<<<B, 256, 0, stream>>>(ctx, hf, Wq, bq, Ws, bs, Wo, bo, logT, out, B);
}